// Round 4
// baseline (16.006 us; speedup 1.0000x reference)
//
#include <hip/hip_runtime.h>

#define NB 512      // batch
#define ND 128      // dim
#define TALPHA 0.2f

// One block per TWO anchors (a0 = 2*bid, a1 = a0+1). 512 threads = 8 waves.
// Each x float4 load feeds BOTH anchors' dot products -> halves L2 traffic.
__global__ __launch_bounds__(512) void triplet_mine_kernel(
    const float* __restrict__ x,       // [NB][ND]
    const int*   __restrict__ target,  // [NB]
    const float* __restrict__ noise,   // [NB][NB][NB]
    float*       __restrict__ partial) // [NB]
{
    const int a0   = blockIdx.x * 2;
    const int a1   = a0 + 1;
    const int tid  = threadIdx.x;
    const int lane = tid & 63;
    const int wv   = tid >> 6;          // 0..7

    __shared__ __align__(16) float d_row[2][NB];
    __shared__ __align__(16) int   tgt[NB];
    __shared__ int   plist[2 * NB];     // packed (sel<<16)|p
    __shared__ int   pcnt_w[2][8];
    __shared__ float wacc_s[8][2];

    const int t_mine = target[tid];
    const int ta0    = target[a0];
    const int ta1    = target[a1];
    tgt[tid] = t_mine;

    // ---- ballot-compact positives for both anchors ----
    const bool m0 = (t_mine == ta0) && (tid != a0);
    const bool m1 = (t_mine == ta1) && (tid != a1);
    const unsigned long long b0 = __ballot(m0);
    const unsigned long long b1 = __ballot(m1);
    if (lane == 0) { pcnt_w[0][wv] = __popcll(b0); pcnt_w[1][wv] = __popcll(b1); }
    __syncthreads();

    int base0 = 0, npos0 = 0, base1 = 0, npos1 = 0;
    #pragma unroll
    for (int w = 0; w < 8; ++w) {
        base0 += (w < wv) ? pcnt_w[0][w] : 0;  npos0 += pcnt_w[0][w];
        base1 += (w < wv) ? pcnt_w[1][w] : 0;  npos1 += pcnt_w[1][w];
    }
    if (m0) {
        const unsigned long long lo = b0 & ((1ull << lane) - 1ull);
        plist[base0 + __popcll(lo)] = tid;                  // sel = 0
    }
    if (m1) {
        const unsigned long long lo = b1 & ((1ull << lane) - 1ull);
        plist[npos0 + base1 + __popcll(lo)] = (1 << 16) | tid;
    }
    __syncthreads();
    const int npos = npos0 + npos1;

    // ---- prefetch this wave's first noise row (hides HBM under d-compute) ----
    float4 nv0, nv1;
    int ecur = 0;
    if (wv < npos) {
        ecur = plist[wv];
        const int sel = ecur >> 16;
        const int p   = ecur & 0xffff;
        const float* nr = noise + ((size_t)(sel ? a1 : a0) * NB + (size_t)p) * NB;
        nv0 = *reinterpret_cast<const float4*>(nr + 4 * lane);
        nv1 = *reinterpret_cast<const float4*>(nr + 256 + 4 * lane);
    }

    // ---- coalesced d-row compute for BOTH anchors ----
    const int c    = lane & 3;
    const int rgrp = lane >> 2;
    const float4* xf4 = reinterpret_cast<const float4*>(x);

    float4 xa0[8], xa1[8];
    #pragma unroll
    for (int j = 0; j < 8; ++j) {
        xa0[j] = xf4[(size_t)a0 * 32 + j * 4 + c];
        xa1[j] = xf4[(size_t)a1 * 32 + j * 4 + c];
    }

    #pragma unroll
    for (int q = 0; q < 4; ++q) {
        const int row = q * 128 + wv * 16 + rgrp;
        const float4* rf4 = xf4 + (size_t)row * 32;
        float acc0 = 0.0f, acc1 = 0.0f;
        #pragma unroll
        for (int j = 0; j < 8; ++j) {
            const float4 v = rf4[j * 4 + c];
            acc0 += xa0[j].x * v.x + xa0[j].y * v.y + xa0[j].z * v.z + xa0[j].w * v.w;
            acc1 += xa1[j].x * v.x + xa1[j].y * v.y + xa1[j].z * v.z + xa1[j].w * v.w;
        }
        acc0 += __shfl_xor(acc0, 1);  acc0 += __shfl_xor(acc0, 2);
        acc1 += __shfl_xor(acc1, 1);  acc1 += __shfl_xor(acc1, 2);
        if (c == 0) {
            d_row[0][row] = 2.0f - 2.0f * acc0;
            d_row[1][row] = 2.0f - 2.0f * acc1;
        }
    }
    __syncthreads();

    // ---- per-wave mining over the merged positive list ----
    const float4* dA4 = reinterpret_cast<const float4*>(d_row[0]);
    const float4* dB4 = reinterpret_cast<const float4*>(d_row[1]);
    const int4*   t4  = reinterpret_cast<const int4*>(tgt);
    const float4 dA0 = dA4[lane], dA1 = dA4[64 + lane];
    const float4 dB0 = dB4[lane], dB1 = dB4[64 + lane];
    const int4   tt0 = t4[lane],  tt1 = t4[64 + lane];

    float wacc0 = 0.0f, wacc1 = 0.0f;

    for (int idx = wv; idx < npos; idx += 8) {
        // prefetch next entry's noise row
        float4 nx0, nx1;
        int enext = 0;
        const int nidx = idx + 8;
        if (nidx < npos) {
            enext = plist[nidx];
            const int sn = enext >> 16;
            const int pn = enext & 0xffff;
            const float* nr = noise + ((size_t)(sn ? a1 : a0) * NB + (size_t)pn) * NB;
            nx0 = *reinterpret_cast<const float4*>(nr + 4 * lane);
            nx1 = *reinterpret_cast<const float4*>(nr + 256 + 4 * lane);
        }

        const int sel = ecur >> 16;          // wave-uniform
        const int p   = ecur & 0xffff;
        const int taS = sel ? ta1 : ta0;
        const float4 dd0 = sel ? dB0 : dA0;
        const float4 dd1 = sel ? dB1 : dA1;
        const float d_ap = sel ? d_row[1][p] : d_row[0][p];

        float bs = -1.0f;   // non-candidate sentinel (noise >= 0)
        int   bn = NB;

        // ascending-n within lane; strict > keeps lowest n on ties
        #define EVAL(nn, dn, tn, sv)                                   \
        {                                                              \
            const float L = d_ap - (dn) + TALPHA;                      \
            if ((L > 0.0f) & (L < TALPHA) & ((tn) != taS)) {           \
                if ((sv) > bs) { bs = (sv); bn = (nn); }               \
            }                                                          \
        }
        EVAL(4*lane + 0,       dd0.x, tt0.x, nv0.x);
        EVAL(4*lane + 1,       dd0.y, tt0.y, nv0.y);
        EVAL(4*lane + 2,       dd0.z, tt0.z, nv0.z);
        EVAL(4*lane + 3,       dd0.w, tt0.w, nv0.w);
        EVAL(256 + 4*lane + 0, dd1.x, tt1.x, nv1.x);
        EVAL(256 + 4*lane + 1, dd1.y, tt1.y, nv1.y);
        EVAL(256 + 4*lane + 2, dd1.z, tt1.z, nv1.z);
        EVAL(256 + 4*lane + 3, dd1.w, tt1.w, nv1.w);
        #undef EVAL

        // butterfly argmax across 64 lanes; tie -> lower n (jnp.argmax order)
        #pragma unroll
        for (int off = 1; off < 64; off <<= 1) {
            const float os = __shfl_xor(bs, off);
            const int   on = __shfl_xor(bn, off);
            if (os > bs || (os == bs && on < bn)) { bs = os; bn = on; }
        }

        if (bs >= 0.0f) {   // has_cand
            const float dn = sel ? d_row[1][bn] : d_row[0][bn];
            const float L  = d_ap - dn + TALPHA;   // in (0, ALPHA)
            if (sel) wacc1 += L; else wacc0 += L;
        }

        ecur = enext; nv0 = nx0; nv1 = nx1;
    }

    if (lane == 0) { wacc_s[wv][0] = wacc0; wacc_s[wv][1] = wacc1; }
    __syncthreads();
    if (tid < 2) {
        float s = 0.0f;
        #pragma unroll
        for (int w = 0; w < 8; ++w) s += wacc_s[w][tid];
        partial[(tid == 0) ? a0 : a1] = s;
    }
}

// deterministic single-wave reduction of 512 partials
__global__ __launch_bounds__(64) void triplet_reduce_kernel(
    const float* __restrict__ partial, float* __restrict__ out)
{
    const int lane = threadIdx.x;
    float s = 0.0f;
    #pragma unroll
    for (int j = 0; j < 8; ++j) s += partial[lane + 64 * j];
    #pragma unroll
    for (int off = 1; off < 64; off <<= 1) s += __shfl_xor(s, off);
    if (lane == 0) out[0] = s;
}

extern "C" void kernel_launch(void* const* d_in, const int* in_sizes, int n_in,
                              void* d_out, int out_size, void* d_ws, size_t ws_size,
                              hipStream_t stream) {
    const float* x      = (const float*)d_in[0];
    const int*   target = (const int*)d_in[1];
    const float* noise  = (const float*)d_in[2];
    float* out     = (float*)d_out;
    float* partial = (float*)d_ws;   // 512 floats of scratch

    triplet_mine_kernel<<<NB / 2, 512, 0, stream>>>(x, target, noise, partial);
    triplet_reduce_kernel<<<1, 64, 0, stream>>>(partial, out);
}